// Round 6
// baseline (230.862 us; speedup 1.0000x reference)
//
#include <hip/hip_runtime.h>
#include <hip/hip_bf16.h>
#include <math.h>

#define N_NODES 50000
#define N_EDGES 640000
#define IN_DIM 5
#define HID 128
#define NGRAPH 512
#define BUCKET 64                           // max degree slots; Poisson(12.8), max obs deg ~40
#define GEMM_NBLK ((N_NODES + 63) / 64)     // 782
#define EDGE_BLK (N_EDGES / 1024)           // 625 (int4 x 256 threads)
#define TPREP_BLK 32                        // W1 transpose, float4 x 256 threads
#define NROW_BLK ((N_NODES + 255) / 256)    // 196

typedef unsigned short u16;
typedef __attribute__((ext_vector_type(8))) short bf16x8;
typedef __attribute__((ext_vector_type(8))) unsigned short u16x8;
typedef __attribute__((ext_vector_type(4))) float f32x4;
typedef __attribute__((ext_vector_type(8))) float f32x8;

__device__ __forceinline__ float bf2f(u16 u) {
  union { unsigned int i; float f; } v; v.i = ((unsigned int)u) << 16; return v.f;
}
__device__ __forceinline__ u16 f2bf(float f) {
  return __bfloat16_as_ushort(__float2bfloat16(f));
}

// ---------------- Fused setup: ONE vectorized edge pass (bucket-CSR; int4, 4 edges/thread)
// + W1 prep (float4) + wvecs + nrow. (R5 lesson: CAS open-addressing regressed; the
// bound is 32B write-transaction BW, and CAS didn't cut bytes.) ----
__global__ __launch_bounds__(256) void setup_k(const int* __restrict__ src,
                                               const int* __restrict__ dst,
                                               int* __restrict__ cnt,
                                               int* __restrict__ slot,
                                               const float* __restrict__ W1rel,
                                               const float* __restrict__ W1root,
                                               u16* __restrict__ T1rel, u16* __restrict__ T1root,
                                               const float* __restrict__ Wrel2,
                                               const float* __restrict__ Wroot2,
                                               const float* __restrict__ b2,
                                               const float* __restrict__ Wlin,
                                               float* __restrict__ wvecs,
                                               const int* __restrict__ batch,
                                               int* __restrict__ nrow) {
  int b = blockIdx.x;
  if (b < EDGE_BLK) {
    int e0 = (b * 256 + threadIdx.x) * 4;
    int4 s4 = *(const int4*)(src + e0);
    int4 d4 = *(const int4*)(dst + e0);
    int ss[4] = {s4.x, s4.y, s4.z, s4.w};
    int dd[4] = {d4.x, d4.y, d4.z, d4.w};
#pragma unroll
    for (int j = 0; j < 4; ++j) {
      int pos = atomicAdd(&cnt[dd[j]], 1);
      if (pos < BUCKET) slot[(size_t)dd[j] * BUCKET + pos] = ss[j];
    }
  } else if (b < EDGE_BLK + TPREP_BLK) {
    int idx4 = ((b - EDGE_BLK) * 256 + threadIdx.x) * 4;
    int which = idx4 >> 14;                 // HID*HID = 16384
    int i = idx4 & (HID * HID - 1);         // k*128 + n, n%4==0
    const float* W = which == 0 ? W1rel : W1root;
    u16* T = which == 0 ? T1rel : T1root;
    int k = i >> 7, n = i & 127;
    float4 w4 = *(const float4*)(W + i);
    T[(n + 0) * HID + k] = f2bf(w4.x);
    T[(n + 1) * HID + k] = f2bf(w4.y);
    T[(n + 2) * HID + k] = f2bf(w4.z);
    T[(n + 3) * HID + k] = f2bf(w4.w);
  } else if (b == EDGE_BLK + TPREP_BLK) {
    int t = threadIdx.x;
    if (t < 128) {
      float s = 0.f;
      for (int c = 0; c < HID; ++c) s = fmaf(Wrel2[t * HID + c], Wlin[c], s);
      wvecs[t] = s;
    } else {
      int k = t - 128;
      float s = 0.f;
      for (int c = 0; c < HID; ++c) s = fmaf(Wroot2[k * HID + c], Wlin[c], s);
      wvecs[128 + k] = s;
    }
    if (t == 0) {
      float s = 0.f;
      for (int c = 0; c < HID; ++c) s = fmaf(b2[c], Wlin[c], s);
      wvecs[256] = s;
    }
  } else {
    // nrow: graph node boundaries from sorted batch (handles empty graphs)
    int n = (b - EDGE_BLK - TPREP_BLK - 1) * 256 + threadIdx.x;
    if (n < N_NODES) {
      int bg = batch[n];
      int bp = (n == 0) ? -1 : batch[n - 1];
      for (int g = bp + 1; g <= bg; ++g) nrow[g] = n;
      if (n == N_NODES - 1) {
        for (int g = bg + 1; g <= NGRAPH; ++g) nrow[g] = N_NODES;
      }
    }
  }
}

// ---------------- Fused layer-0: CSR x-gather (4 thr/node, shuffle-reduced, NO atomics)
// + dense projection into LDS + layer-1 dual MFMA GEMM. A5/HA never touch HBM. ----
__global__ __launch_bounds__(256, 3) void proj_gemm_k(const float* __restrict__ x,
                                                      const int* __restrict__ cnt,
                                                      const int* __restrict__ slot,
                                                      const float* __restrict__ Wrel0,
                                                      const float* __restrict__ Wroot0,
                                                      const float* __restrict__ brel0,
                                                      const u16* __restrict__ WrelT,
                                                      const u16* __restrict__ WrootT,
                                                      const float* __restrict__ bias1,
                                                      u16* __restrict__ Z,
                                                      u16* __restrict__ R) {
  __shared__ u16 As[64][136];
  __shared__ float A5s[64][IN_DIM];
  const int tid = threadIdx.x;
  const int r0 = blockIdx.x * 64;

  // ---- x-aggregation for this block's 64 rows: 4 threads per node ----
  {
    const int li = tid >> 2;     // 0..63 local node
    const int l4 = tid & 3;
    const int node = r0 + li;
    float a[IN_DIM];
#pragma unroll
    for (int k = 0; k < IN_DIM; ++k) a[k] = 0.f;
    if (node < N_NODES) {
      int deg = min(cnt[node], BUCKET);
      size_t base = (size_t)node * BUCKET;
      for (int j = l4; j < deg; j += 4) {
        int s = slot[base + j];
#pragma unroll
        for (int k = 0; k < IN_DIM; ++k) a[k] += x[s * IN_DIM + k];
      }
    }
#pragma unroll
    for (int k = 0; k < IN_DIM; ++k) {
      a[k] += __shfl_xor(a[k], 1, 64);
      a[k] += __shfl_xor(a[k], 2, 64);
    }
    if (l4 == 0) {
#pragma unroll
      for (int k = 0; k < IN_DIM; ++k) A5s[li][k] = a[k];
    }
  }
  __syncthreads();

  // ---- dense layer-0: each thread computes 16 rows x 2 cols of relu(conv0) ----
  {
    const int c0 = (tid & 63) * 2;   // column pair
    const int rg = tid >> 6;         // row group (wave id)
    float wr0[IN_DIM], wr1[IN_DIM], wo0[IN_DIM], wo1[IN_DIM];
#pragma unroll
    for (int k = 0; k < IN_DIM; ++k) {
      wr0[k] = Wrel0[k * HID + c0];
      wr1[k] = Wrel0[k * HID + c0 + 1];
      wo0[k] = Wroot0[k * HID + c0];
      wo1[k] = Wroot0[k * HID + c0 + 1];
    }
    const float b0 = brel0[c0], b1 = brel0[c0 + 1];
#pragma unroll
    for (int i = 0; i < 16; ++i) {
      int row = rg * 16 + i;
      int grow = r0 + row;
      float v0 = 0.f, v1 = 0.f;
      if (grow < N_NODES) {
        v0 = b0; v1 = b1;
#pragma unroll
        for (int k = 0; k < IN_DIM; ++k) {
          float a = A5s[row][k];
          float xr = x[grow * IN_DIM + k];
          v0 = fmaf(a, wr0[k], fmaf(xr, wo0[k], v0));
          v1 = fmaf(a, wr1[k], fmaf(xr, wo1[k], v1));
        }
      }
      ushort2 w2;
      w2.x = f2bf(fmaxf(v0, 0.f));
      w2.y = f2bf(fmaxf(v1, 0.f));
      *(ushort2*)&As[row][c0] = w2;
    }
  }
  __syncthreads();

  // ---- MFMA phase (verified layout): wv 0,1 -> Z cols 0..63/64..127; wv 2,3 -> R ----
  const int wv = tid >> 6, lane = tid & 63;
  const int m = lane & 15, quad = lane >> 4;
  const u16* WT = (wv < 2) ? WrelT : WrootT;
  const int n0 = (wv & 1) * 64;

  f32x4 acc[4][4];
#pragma unroll
  for (int mt = 0; mt < 4; ++mt)
#pragma unroll
    for (int nt = 0; nt < 4; ++nt) acc[mt][nt] = (f32x4){0.f, 0.f, 0.f, 0.f};

#pragma unroll
  for (int ks = 0; ks < 4; ++ks) {
    int kb = ks * 32;
    bf16x8 af[4], bf[4];
#pragma unroll
    for (int mt = 0; mt < 4; ++mt)
      af[mt] = *(const bf16x8*)&As[mt * 16 + m][kb + quad * 8];
#pragma unroll
    for (int nt = 0; nt < 4; ++nt)
      bf[nt] = *(const bf16x8*)(WT + (size_t)(n0 + nt * 16 + m) * HID + kb + quad * 8);
#pragma unroll
    for (int mt = 0; mt < 4; ++mt)
#pragma unroll
      for (int nt = 0; nt < 4; ++nt)
        acc[mt][nt] = __builtin_amdgcn_mfma_f32_16x16x32_bf16(af[mt], bf[nt], acc[mt][nt], 0, 0, 0);
  }

  if (wv < 2) {
#pragma unroll
    for (int mt = 0; mt < 4; ++mt)
#pragma unroll
      for (int nt = 0; nt < 4; ++nt) {
        int col = n0 + nt * 16 + m;
#pragma unroll
        for (int r = 0; r < 4; ++r) {
          int row = r0 + mt * 16 + quad * 4 + r;
          if (row < N_NODES) Z[(size_t)row * HID + col] = f2bf(acc[mt][nt][r]);
        }
      }
  } else {
    float bl[4];
#pragma unroll
    for (int nt = 0; nt < 4; ++nt) bl[nt] = bias1[n0 + nt * 16 + m];
#pragma unroll
    for (int mt = 0; mt < 4; ++mt)
#pragma unroll
      for (int nt = 0; nt < 4; ++nt) {
        int col = n0 + nt * 16 + m;
#pragma unroll
        for (int r = 0; r < 4; ++r) {
          int row = r0 + mt * 16 + quad * 4 + r;
          if (row < N_NODES) R[(size_t)row * HID + col] = f2bf(acc[mt][nt][r] + bl[nt]);
        }
      }
  }
}

// ---------------- Layer-1 agg + layer-2 scalar collapse, COLUMN-BLOCKED ----------------
// 4 phases x 32 dims: per-phase Z working set is a 3.2MB column block -> per-XCD
// L2-resident (vs 12.8MB full rows at ~25% hit rate). relu is elementwise and s is a
// dot product, so per-phase partials are exact. Slot row register-cached + shfl.
__global__ __launch_bounds__(256) void agg_s_k(const u16* __restrict__ Z,
                                               const int* __restrict__ cnt,
                                               const int* __restrict__ slot,
                                               const u16* __restrict__ R,
                                               const float* __restrict__ wvecs,
                                               float* __restrict__ s_rel,
                                               float* __restrict__ s_root) {
  int wave = threadIdx.x >> 6;
  int lane = threadIdx.x & 63;
  int node = blockIdx.x * 4 + wave;
  if (node >= N_NODES) return;
  int q = lane >> 4;
  int l16 = lane & 15;
  int deg = min(cnt[node], BUCKET);                 // wave-uniform
  int myslot = (lane < deg) ? slot[(size_t)node * BUCKET + lane] : -1;
  int Tmax = (deg + 3) >> 2;                        // edges per q-group (uniform bound)
  float sr = 0.f, so = 0.f;
#pragma unroll
  for (int c = 0; c < 4; ++c) {
    const int d0 = c * 32 + l16 * 2;                // dim pair this lane covers
    float a0 = 0.f, a1 = 0.f, b0 = 0.f, b1 = 0.f;
    for (int t = 0; t < Tmax; t += 2) {
      int j0 = q + 4 * t;
      int j1 = j0 + 4;
      int s0 = __shfl(myslot, j0 & 63, 64);         // uniform shfl; guard after
      int s1 = __shfl(myslot, j1 & 63, 64);
      if (j0 < deg) {
        ushort2 za = *(const ushort2*)(Z + (size_t)s0 * HID + d0);
        a0 += bf2f(za.x); a1 += bf2f(za.y);
      }
      if (j1 < deg) {
        ushort2 zb = *(const ushort2*)(Z + (size_t)s1 * HID + d0);
        b0 += bf2f(zb.x); b1 += bf2f(zb.y);
      }
    }
    a0 += b0; a1 += b1;
    a0 += __shfl_xor(a0, 16, 64); a0 += __shfl_xor(a0, 32, 64);
    a1 += __shfl_xor(a1, 16, 64); a1 += __shfl_xor(a1, 32, 64);
    if (q == 0) {
      ushort2 r2 = *(const ushort2*)(R + (size_t)node * HID + d0);
      float h0 = fmaxf(bf2f(r2.x) + a0, 0.f);
      float h1 = fmaxf(bf2f(r2.y) + a1, 0.f);
      sr = fmaf(h0, wvecs[d0], fmaf(h1, wvecs[d0 + 1], sr));
      so = fmaf(h0, wvecs[128 + d0], fmaf(h1, wvecs[128 + d0 + 1], so));
    }
  }
  if (q == 0) {
#pragma unroll
    for (int w = 1; w < 16; w <<= 1) {
      sr += __shfl_xor(sr, w, 16);
      so += __shfl_xor(so, w, 16);
    }
    if (l16 == 0) {
      s_rel[node] = sr;
      s_root[node] = so;
    }
  }
}

// ---------------- Block-per-graph pooled reduction + head (NO atomics) ----------------
__global__ __launch_bounds__(256) void pool_final_k(const float* __restrict__ s_rel,
                                                    const float* __restrict__ s_root,
                                                    const int* __restrict__ cnt,
                                                    const int* __restrict__ slot,
                                                    const int* __restrict__ nrow,
                                                    const float* __restrict__ wvecs,
                                                    const float* __restrict__ blin,
                                                    float* __restrict__ out) {
  int g = blockIdx.x;
  int n0 = nrow[g], n1 = nrow[g + 1];
  int wave = threadIdx.x >> 6;
  int lane = threadIdx.x & 63;
  float s = 0.f;
  for (int n = n0 + wave; n < n1; n += 4) {
    int deg = min(cnt[n], BUCKET);
    if (lane < deg) s += s_rel[slot[(size_t)n * BUCKET + lane]];
  }
  for (int n = n0 + threadIdx.x; n < n1; n += 256) s += s_root[n];
  __shared__ float red[4];
#pragma unroll
  for (int w = 32; w; w >>= 1) s += __shfl_down(s, w, 64);
  if (lane == 0) red[wave] = s;
  __syncthreads();
  if (threadIdx.x == 0) {
    float t = red[0] + red[1] + red[2] + red[3];
    float cntf = (float)(n1 - n0);
    float cmax = fmaxf(cntf, 1.f);
    float logit = (t + cntf * wvecs[256]) / cmax + blin[0];
    out[g] = 1.f / (1.f + expf(-logit));
  }
}

// ================= host launch =================

extern "C" void kernel_launch(void* const* d_in, const int* in_sizes, int n_in,
                              void* d_out, int out_size, void* d_ws, size_t ws_size,
                              hipStream_t stream) {
  const float* x      = (const float*)d_in[0];
  const int*   ei     = (const int*)d_in[1];
  const int*   batch  = (const int*)d_in[2];
  const float* Wrel0  = (const float*)d_in[3];
  const float* brel0  = (const float*)d_in[4];
  const float* Wroot0 = (const float*)d_in[5];
  const float* Wrel1  = (const float*)d_in[6];
  const float* brel1  = (const float*)d_in[7];
  const float* Wroot1 = (const float*)d_in[8];
  const float* Wrel2  = (const float*)d_in[9];
  const float* brel2  = (const float*)d_in[10];
  const float* Wroot2 = (const float*)d_in[11];
  const float* Wlin   = (const float*)d_in[12];
  const float* blin   = (const float*)d_in[13];
  float* out = (float*)d_out;
  const int* srcp = ei;
  const int* dstp = ei + N_EDGES;

  char* ws = (char*)d_ws;
  size_t off = 0;
  auto alloc = [&](size_t b) { size_t o = off; off += (b + 255) & ~(size_t)255; return (void*)(ws + o); };
  u16*  Z      = (u16*)alloc(sizeof(u16) * N_NODES * HID);
  u16*  R      = (u16*)alloc(sizeof(u16) * N_NODES * HID);
  float* s_rel  = (float*)alloc(sizeof(float) * N_NODES);
  float* s_root = (float*)alloc(sizeof(float) * N_NODES);
  u16* WT1rel  = (u16*)alloc(sizeof(u16) * HID * HID);
  u16* WT1root = (u16*)alloc(sizeof(u16) * HID * HID);
  float* wvecs = (float*)alloc(sizeof(float) * 260);
  int* nrow    = (int*)alloc(sizeof(int) * (NGRAPH + 1));
  int* slot    = (int*)alloc(sizeof(int) * (size_t)N_NODES * BUCKET);  // 12.8 MB bucket CSR
  // zero region: cnt only (200 KB)
  size_t zero_base = off;
  int*   cnt  = (int*)alloc(sizeof(int) * N_NODES);
  size_t zero_len = off - zero_base;

  hipMemsetAsync(ws + zero_base, 0, zero_len, stream);

  setup_k<<<EDGE_BLK + TPREP_BLK + 1 + NROW_BLK, 256, 0, stream>>>(
      srcp, dstp, cnt, slot, Wrel1, Wroot1, WT1rel, WT1root,
      Wrel2, Wroot2, brel2, Wlin, wvecs, batch, nrow);
  proj_gemm_k<<<GEMM_NBLK, 256, 0, stream>>>(x, cnt, slot, Wrel0, Wroot0, brel0,
                                             WT1rel, WT1root, brel1, Z, R);
  agg_s_k<<<(N_NODES + 3) / 4, 256, 0, stream>>>(Z, cnt, slot, R, wvecs, s_rel, s_root);
  pool_final_k<<<NGRAPH, 256, 0, stream>>>(s_rel, s_root, cnt, slot, nrow, wvecs, blin, out);
}

// Round 7
// 203.097 us; speedup vs baseline: 1.1367x; 1.1367x over previous
//
#include <hip/hip_runtime.h>
#include <hip/hip_bf16.h>
#include <math.h>

#define N_NODES 50000
#define N_EDGES 640000
#define IN_DIM 5
#define HID 128
#define NGRAPH 512
#define BUCKET 64                           // max degree slots; Poisson(12.8), max obs deg ~40
#define GEMM_NBLK ((N_NODES + 63) / 64)     // 782
#define EDGE_BLK (N_EDGES / 1024)           // 625 (int4 x 256 threads)
#define TPREP_BLK 32                        // W1 transpose, float4 x 256 threads
#define NROW_BLK ((N_NODES + 255) / 256)    // 196

typedef unsigned short u16;
typedef __attribute__((ext_vector_type(8))) short bf16x8;
typedef __attribute__((ext_vector_type(8))) unsigned short u16x8;
typedef __attribute__((ext_vector_type(4))) float f32x4;
typedef __attribute__((ext_vector_type(8))) float f32x8;
// under-aligned float4 for 20B-stride x rows (lowers to one dwordx4 load)
typedef __attribute__((ext_vector_type(4), aligned(4))) float f32x4u;

__device__ __forceinline__ float bf2f(u16 u) {
  union { unsigned int i; float f; } v; v.i = ((unsigned int)u) << 16; return v.f;
}
__device__ __forceinline__ u16 f2bf(float f) {
  return __bfloat16_as_ushort(__float2bfloat16(f));
}

// ---------------- Fused setup: ONE vectorized edge pass (bucket-CSR; int4, 4 edges/thread)
// + W1 prep (float4) + wvecs + nrow. (R5: CAS regressed — bound is write-txn BW.) ----
__global__ __launch_bounds__(256) void setup_k(const int* __restrict__ src,
                                               const int* __restrict__ dst,
                                               int* __restrict__ cnt,
                                               int* __restrict__ slot,
                                               const float* __restrict__ W1rel,
                                               const float* __restrict__ W1root,
                                               u16* __restrict__ T1rel, u16* __restrict__ T1root,
                                               const float* __restrict__ Wrel2,
                                               const float* __restrict__ Wroot2,
                                               const float* __restrict__ b2,
                                               const float* __restrict__ Wlin,
                                               float* __restrict__ wvecs,
                                               const int* __restrict__ batch,
                                               int* __restrict__ nrow) {
  int b = blockIdx.x;
  if (b < EDGE_BLK) {
    int e0 = (b * 256 + threadIdx.x) * 4;
    int4 s4 = *(const int4*)(src + e0);
    int4 d4 = *(const int4*)(dst + e0);
    int ss[4] = {s4.x, s4.y, s4.z, s4.w};
    int dd[4] = {d4.x, d4.y, d4.z, d4.w};
#pragma unroll
    for (int j = 0; j < 4; ++j) {
      int pos = atomicAdd(&cnt[dd[j]], 1);
      if (pos < BUCKET) slot[(size_t)dd[j] * BUCKET + pos] = ss[j];
    }
  } else if (b < EDGE_BLK + TPREP_BLK) {
    int idx4 = ((b - EDGE_BLK) * 256 + threadIdx.x) * 4;
    int which = idx4 >> 14;                 // HID*HID = 16384
    int i = idx4 & (HID * HID - 1);         // k*128 + n, n%4==0
    const float* W = which == 0 ? W1rel : W1root;
    u16* T = which == 0 ? T1rel : T1root;
    int k = i >> 7, n = i & 127;
    float4 w4 = *(const float4*)(W + i);
    T[(n + 0) * HID + k] = f2bf(w4.x);
    T[(n + 1) * HID + k] = f2bf(w4.y);
    T[(n + 2) * HID + k] = f2bf(w4.z);
    T[(n + 3) * HID + k] = f2bf(w4.w);
  } else if (b == EDGE_BLK + TPREP_BLK) {
    int t = threadIdx.x;
    if (t < 128) {
      float s = 0.f;
      for (int c = 0; c < HID; ++c) s = fmaf(Wrel2[t * HID + c], Wlin[c], s);
      wvecs[t] = s;
    } else {
      int k = t - 128;
      float s = 0.f;
      for (int c = 0; c < HID; ++c) s = fmaf(Wroot2[k * HID + c], Wlin[c], s);
      wvecs[128 + k] = s;
    }
    if (t == 0) {
      float s = 0.f;
      for (int c = 0; c < HID; ++c) s = fmaf(b2[c], Wlin[c], s);
      wvecs[256] = s;
    }
  } else {
    // nrow: graph node boundaries from sorted batch (handles empty graphs)
    int n = (b - EDGE_BLK - TPREP_BLK - 1) * 256 + threadIdx.x;
    if (n < N_NODES) {
      int bg = batch[n];
      int bp = (n == 0) ? -1 : batch[n - 1];
      for (int g = bp + 1; g <= bg; ++g) nrow[g] = n;
      if (n == N_NODES - 1) {
        for (int g = bg + 1; g <= NGRAPH; ++g) nrow[g] = N_NODES;
      }
    }
  }
}

// ---------------- Fused layer-0: CSR x-gather (4 thr/node, shuffle-reduced, NO atomics)
// + dense projection into LDS + layer-1 dual MFMA GEMM. A5/HA never touch HBM. ----
__global__ __launch_bounds__(256, 3) void proj_gemm_k(const float* __restrict__ x,
                                                      const int* __restrict__ cnt,
                                                      const int* __restrict__ slot,
                                                      const float* __restrict__ Wrel0,
                                                      const float* __restrict__ Wroot0,
                                                      const float* __restrict__ brel0,
                                                      const u16* __restrict__ WrelT,
                                                      const u16* __restrict__ WrootT,
                                                      const float* __restrict__ bias1,
                                                      u16* __restrict__ Z,
                                                      u16* __restrict__ R) {
  __shared__ u16 As[64][136];
  __shared__ float A5s[64][IN_DIM];
  const int tid = threadIdx.x;
  const int r0 = blockIdx.x * 64;

  // ---- x-aggregation for this block's 64 rows: 4 threads per node ----
  {
    const int li = tid >> 2;     // 0..63 local node
    const int l4 = tid & 3;
    const int node = r0 + li;
    float a[IN_DIM];
#pragma unroll
    for (int k = 0; k < IN_DIM; ++k) a[k] = 0.f;
    if (node < N_NODES) {
      int deg = min(cnt[node], BUCKET);
      size_t base = (size_t)node * BUCKET;
      for (int j = l4; j < deg; j += 4) {
        int s = slot[base + j];
        f32x4u xv = *(const f32x4u*)(x + (size_t)s * IN_DIM);   // 1 dwordx4
        float x4 = x[(size_t)s * IN_DIM + 4];                    // + 1 dword
#pragma unroll
        for (int k = 0; k < 4; ++k) a[k] += xv[k];
        a[4] += x4;
      }
    }
#pragma unroll
    for (int k = 0; k < IN_DIM; ++k) {
      a[k] += __shfl_xor(a[k], 1, 64);
      a[k] += __shfl_xor(a[k], 2, 64);
    }
    if (l4 == 0) {
#pragma unroll
      for (int k = 0; k < IN_DIM; ++k) A5s[li][k] = a[k];
    }
  }
  __syncthreads();

  // ---- dense layer-0: each thread computes 16 rows x 2 cols of relu(conv0) ----
  {
    const int c0 = (tid & 63) * 2;   // column pair
    const int rg = tid >> 6;         // row group (wave id)
    float wr0[IN_DIM], wr1[IN_DIM], wo0[IN_DIM], wo1[IN_DIM];
#pragma unroll
    for (int k = 0; k < IN_DIM; ++k) {
      wr0[k] = Wrel0[k * HID + c0];
      wr1[k] = Wrel0[k * HID + c0 + 1];
      wo0[k] = Wroot0[k * HID + c0];
      wo1[k] = Wroot0[k * HID + c0 + 1];
    }
    const float b0 = brel0[c0], b1 = brel0[c0 + 1];
#pragma unroll
    for (int i = 0; i < 16; ++i) {
      int row = rg * 16 + i;
      int grow = r0 + row;
      float v0 = 0.f, v1 = 0.f;
      if (grow < N_NODES) {
        v0 = b0; v1 = b1;
        f32x4u xv = *(const f32x4u*)(x + (size_t)grow * IN_DIM);
        float x4 = x[(size_t)grow * IN_DIM + 4];
        float xr[IN_DIM] = {xv[0], xv[1], xv[2], xv[3], x4};
#pragma unroll
        for (int k = 0; k < IN_DIM; ++k) {
          float a = A5s[row][k];
          v0 = fmaf(a, wr0[k], fmaf(xr[k], wo0[k], v0));
          v1 = fmaf(a, wr1[k], fmaf(xr[k], wo1[k], v1));
        }
      }
      ushort2 w2;
      w2.x = f2bf(fmaxf(v0, 0.f));
      w2.y = f2bf(fmaxf(v1, 0.f));
      *(ushort2*)&As[row][c0] = w2;
    }
  }
  __syncthreads();

  // ---- MFMA phase (verified layout): wv 0,1 -> Z cols 0..63/64..127; wv 2,3 -> R ----
  const int wv = tid >> 6, lane = tid & 63;
  const int m = lane & 15, quad = lane >> 4;
  const u16* WT = (wv < 2) ? WrelT : WrootT;
  const int n0 = (wv & 1) * 64;

  f32x4 acc[4][4];
#pragma unroll
  for (int mt = 0; mt < 4; ++mt)
#pragma unroll
    for (int nt = 0; nt < 4; ++nt) acc[mt][nt] = (f32x4){0.f, 0.f, 0.f, 0.f};

#pragma unroll
  for (int ks = 0; ks < 4; ++ks) {
    int kb = ks * 32;
    bf16x8 af[4], bf[4];
#pragma unroll
    for (int mt = 0; mt < 4; ++mt)
      af[mt] = *(const bf16x8*)&As[mt * 16 + m][kb + quad * 8];
#pragma unroll
    for (int nt = 0; nt < 4; ++nt)
      bf[nt] = *(const bf16x8*)(WT + (size_t)(n0 + nt * 16 + m) * HID + kb + quad * 8);
#pragma unroll
    for (int mt = 0; mt < 4; ++mt)
#pragma unroll
      for (int nt = 0; nt < 4; ++nt)
        acc[mt][nt] = __builtin_amdgcn_mfma_f32_16x16x32_bf16(af[mt], bf[nt], acc[mt][nt], 0, 0, 0);
  }

  if (wv < 2) {
#pragma unroll
    for (int mt = 0; mt < 4; ++mt)
#pragma unroll
      for (int nt = 0; nt < 4; ++nt) {
        int col = n0 + nt * 16 + m;
#pragma unroll
        for (int r = 0; r < 4; ++r) {
          int row = r0 + mt * 16 + quad * 4 + r;
          if (row < N_NODES) Z[(size_t)row * HID + col] = f2bf(acc[mt][nt][r]);
        }
      }
  } else {
    float bl[4];
#pragma unroll
    for (int nt = 0; nt < 4; ++nt) bl[nt] = bias1[n0 + nt * 16 + m];
#pragma unroll
    for (int mt = 0; mt < 4; ++mt)
#pragma unroll
      for (int nt = 0; nt < 4; ++nt) {
        int col = n0 + nt * 16 + m;
#pragma unroll
        for (int r = 0; r < 4; ++r) {
          int row = r0 + mt * 16 + quad * 4 + r;
          if (row < N_NODES) R[(size_t)row * HID + col] = f2bf(acc[mt][nt][r] + bl[nt]);
        }
      }
  }
}

// ---- gather helper: unrolled x2, 8 edges in flight per wave (R4-verified, ~32us) ----
__device__ __forceinline__ void gather_node(const u16* __restrict__ Z,
                                            const int* __restrict__ esrc,
                                            int beg, int end, int q, int f8,
                                            f32x8& out) {
  f32x8 a0, a1;
#pragma unroll
  for (int j = 0; j < 8; ++j) { a0[j] = 0.f; a1[j] = 0.f; }
  int e = beg + q;
  for (; e + 4 < end; e += 8) {
    int s0 = esrc[e];
    int s1 = esrc[e + 4];
    u16x8 za = *(const u16x8*)(Z + (size_t)s0 * HID + f8);
    u16x8 zb = *(const u16x8*)(Z + (size_t)s1 * HID + f8);
#pragma unroll
    for (int j = 0; j < 8; ++j) { a0[j] += bf2f(za[j]); a1[j] += bf2f(zb[j]); }
  }
  if (e < end) {
    int s0 = esrc[e];
    u16x8 za = *(const u16x8*)(Z + (size_t)s0 * HID + f8);
#pragma unroll
    for (int j = 0; j < 8; ++j) a0[j] += bf2f(za[j]);
  }
#pragma unroll
  for (int j = 0; j < 8; ++j) out[j] = a0[j] + a1[j];
}

// ---------------- Layer-1 agg + layer-2 scalar collapse (wave per node; R4 form).
// R6 lesson: full-row u16x8 gather ≈ 32us is near the random-gather floor; per-wave
// column-phasing regressed (phases not globally synchronized -> no L2 benefit). ----
__global__ __launch_bounds__(256) void agg_s_k(const u16* __restrict__ Z,
                                               const int* __restrict__ cnt,
                                               const int* __restrict__ slot,
                                               const u16* __restrict__ R,
                                               const float* __restrict__ wvecs,
                                               float* __restrict__ s_rel,
                                               float* __restrict__ s_root) {
  int wave = threadIdx.x >> 6;
  int lane = threadIdx.x & 63;
  int node = blockIdx.x * 4 + wave;
  if (node >= N_NODES) return;
  int q = lane >> 4;
  int l16 = lane & 15;
  int f8 = l16 * 8;
  int beg = node * BUCKET;
  int end = beg + min(cnt[node], BUCKET);
  f32x8 acc;
  gather_node(Z, slot, beg, end, q, f8, acc);
#pragma unroll
  for (int j = 0; j < 8; ++j) {
    acc[j] += __shfl_xor(acc[j], 16, 64);
    acc[j] += __shfl_xor(acc[j], 32, 64);
  }
  if (q == 0) {
    const u16* rp = R + (size_t)node * HID + f8;
    u16x8 r8 = *(const u16x8*)rp;
    float sr = 0.f, so = 0.f;
#pragma unroll
    for (int j = 0; j < 8; ++j) {
      float h = fmaxf(bf2f(r8[j]) + acc[j], 0.f);
      sr = fmaf(h, wvecs[f8 + j], sr);
      so = fmaf(h, wvecs[128 + f8 + j], so);
    }
#pragma unroll
    for (int w = 1; w < 16; w <<= 1) {
      sr += __shfl_xor(sr, w, 16);
      so += __shfl_xor(so, w, 16);
    }
    if (l16 == 0) {
      s_rel[node] = sr;
      s_root[node] = so;
    }
  }
}

// ---------------- Block-per-graph pooled reduction + head (NO atomics) ----------------
__global__ __launch_bounds__(256) void pool_final_k(const float* __restrict__ s_rel,
                                                    const float* __restrict__ s_root,
                                                    const int* __restrict__ cnt,
                                                    const int* __restrict__ slot,
                                                    const int* __restrict__ nrow,
                                                    const float* __restrict__ wvecs,
                                                    const float* __restrict__ blin,
                                                    float* __restrict__ out) {
  int g = blockIdx.x;
  int n0 = nrow[g], n1 = nrow[g + 1];
  int wave = threadIdx.x >> 6;
  int lane = threadIdx.x & 63;
  float s = 0.f;
  for (int n = n0 + wave; n < n1; n += 4) {
    int deg = min(cnt[n], BUCKET);
    if (lane < deg) s += s_rel[slot[(size_t)n * BUCKET + lane]];
  }
  for (int n = n0 + threadIdx.x; n < n1; n += 256) s += s_root[n];
  __shared__ float red[4];
#pragma unroll
  for (int w = 32; w; w >>= 1) s += __shfl_down(s, w, 64);
  if (lane == 0) red[wave] = s;
  __syncthreads();
  if (threadIdx.x == 0) {
    float t = red[0] + red[1] + red[2] + red[3];
    float cntf = (float)(n1 - n0);
    float cmax = fmaxf(cntf, 1.f);
    float logit = (t + cntf * wvecs[256]) / cmax + blin[0];
    out[g] = 1.f / (1.f + expf(-logit));
  }
}

// ================= host launch =================

extern "C" void kernel_launch(void* const* d_in, const int* in_sizes, int n_in,
                              void* d_out, int out_size, void* d_ws, size_t ws_size,
                              hipStream_t stream) {
  const float* x      = (const float*)d_in[0];
  const int*   ei     = (const int*)d_in[1];
  const int*   batch  = (const int*)d_in[2];
  const float* Wrel0  = (const float*)d_in[3];
  const float* brel0  = (const float*)d_in[4];
  const float* Wroot0 = (const float*)d_in[5];
  const float* Wrel1  = (const float*)d_in[6];
  const float* brel1  = (const float*)d_in[7];
  const float* Wroot1 = (const float*)d_in[8];
  const float* Wrel2  = (const float*)d_in[9];
  const float* brel2  = (const float*)d_in[10];
  const float* Wroot2 = (const float*)d_in[11];
  const float* Wlin   = (const float*)d_in[12];
  const float* blin   = (const float*)d_in[13];
  float* out = (float*)d_out;
  const int* srcp = ei;
  const int* dstp = ei + N_EDGES;

  char* ws = (char*)d_ws;
  size_t off = 0;
  auto alloc = [&](size_t b) { size_t o = off; off += (b + 255) & ~(size_t)255; return (void*)(ws + o); };
  u16*  Z      = (u16*)alloc(sizeof(u16) * N_NODES * HID);
  u16*  R      = (u16*)alloc(sizeof(u16) * N_NODES * HID);
  float* s_rel  = (float*)alloc(sizeof(float) * N_NODES);
  float* s_root = (float*)alloc(sizeof(float) * N_NODES);
  u16* WT1rel  = (u16*)alloc(sizeof(u16) * HID * HID);
  u16* WT1root = (u16*)alloc(sizeof(u16) * HID * HID);
  float* wvecs = (float*)alloc(sizeof(float) * 260);
  int* nrow    = (int*)alloc(sizeof(int) * (NGRAPH + 1));
  int* slot    = (int*)alloc(sizeof(int) * (size_t)N_NODES * BUCKET);  // 12.8 MB bucket CSR
  // zero region: cnt only (200 KB)
  size_t zero_base = off;
  int*   cnt  = (int*)alloc(sizeof(int) * N_NODES);
  size_t zero_len = off - zero_base;

  hipMemsetAsync(ws + zero_base, 0, zero_len, stream);

  setup_k<<<EDGE_BLK + TPREP_BLK + 1 + NROW_BLK, 256, 0, stream>>>(
      srcp, dstp, cnt, slot, Wrel1, Wroot1, WT1rel, WT1root,
      Wrel2, Wroot2, brel2, Wlin, wvecs, batch, nrow);
  proj_gemm_k<<<GEMM_NBLK, 256, 0, stream>>>(x, cnt, slot, Wrel0, Wroot0, brel0,
                                             WT1rel, WT1root, brel1, Z, R);
  agg_s_k<<<(N_NODES + 3) / 4, 256, 0, stream>>>(Z, cnt, slot, R, wvecs, s_rel, s_root);
  pool_final_k<<<NGRAPH, 256, 0, stream>>>(s_rel, s_root, cnt, slot, nrow, wvecs, blin, out);
}